// Round 2
// baseline (812.398 us; speedup 1.0000x reference)
//
#include <hip/hip_runtime.h>
#include <math.h>

#define BB 16
#define CC 128
#define HH 128
#define WW 128
#define H2 64
#define W2 64
#define LL 4096   // 64*64

// ws layout (floats): guide [BB*CC*LL] | S [BB*CC*5] | attn [BB*CC*5]

__device__ __forceinline__ float dot4(float4 wv, float4 av) {
    return wv.x*av.x + wv.y*av.y + wv.z*av.z + wv.w*av.w;
}

__global__ __launch_bounds__(256) void zero_S(float* __restrict__ S) {
    int i = blockIdx.x*256 + threadIdx.x;
    if (i < BB*CC*5) S[i] = 0.f;
}

// ---- guide = dwconv7x7_s2(gelu(bn(x))) ----
__global__ __launch_bounds__(256) void guide_kernel(
    const float* __restrict__ x, const float* __restrict__ gamma,
    const float* __restrict__ beta, const float* __restrict__ mean,
    const float* __restrict__ var, const float* __restrict__ dww,
    const float* __restrict__ dwb, float* __restrict__ guide)
{
    int bc = blockIdx.x;
    int b = bc >> 7, c = bc & 127;
    int tile = blockIdx.y;
    int th0 = (tile >> 2) << 4, tw0 = (tile & 3) << 4;   // 16x16 output tile
    __shared__ float g[38][40];
    __shared__ float wsh[49];
    int t = threadIdx.x;
    if (t < 49) wsh[t] = dww[c*49 + t];
    float scl = gamma[c] * rsqrtf(var[c] + 1e-5f);
    float sft = beta[c] - mean[c]*scl;
    const float* xb = x + (size_t)(b*CC + c)*HH*WW;
    int ih0 = 2*th0 - 3, iw0 = 2*tw0 - 3;
    for (int idx = t; idx < 38*38; idx += 256) {
        int r = idx / 38, q = idx - r*38;
        int ih = ih0 + r, iw = iw0 + q;
        float v = 0.f;
        if ((unsigned)ih < (unsigned)HH && (unsigned)iw < (unsigned)WW) {
            float xv = xb[ih*WW + iw];
            xv = xv*scl + sft;                       // BN (eval)
            v = 0.5f*xv*(1.f + erff(xv*0.70710678118654752f));  // exact GELU
        }
        g[r][q] = v;   // zero-padding applied AFTER gelu (pads g, not x)
    }
    __syncthreads();
    int ol = t >> 4, ow = t & 15;
    float acc = dwb[c];
    #pragma unroll
    for (int kh = 0; kh < 7; ++kh) {
        #pragma unroll
        for (int kw = 0; kw < 7; ++kw)
            acc += wsh[kh*7+kw] * g[2*ol+kh][2*ow+kw];
    }
    guide[(size_t)(b*CC + c)*LL + (th0+ol)*W2 + (tw0+ow)] = acc;
}

// stage 5 tokens for 16 consecutive l (one 16-wide slice of output row h)
// tok[n][l][c]; n=0 guide, n=1..4 unfold phases (s1*2+s2)
__device__ __forceinline__ void stage_tokens(
    float tok[5][16][128], const float* __restrict__ xb,
    const float* __restrict__ gb, int h, int w0, int c, int par)
{
    const float* src0 = gb + (size_t)c*LL + h*W2 + w0 + par*8;
    #pragma unroll
    for (int i = 0; i < 8; ++i) tok[0][par*8 + i][c] = src0[i];
    #pragma unroll
    for (int s1 = 0; s1 < 2; ++s1) {
        const float* src = xb + ((size_t)c*HH + (2*h + s1))*WW + 2*w0 + par*16;
        #pragma unroll
        for (int j = 0; j < 16; ++j) {
            int jj = par*16 + j;
            tok[1 + s1*2 + (jj & 1)][jj >> 1][c] = src[j];
        }
    }
}

// ---- phase A: S[b,c,m] += sum_l q0(c,l)*k_m(c,l) ----
__global__ __launch_bounds__(256) void s_kernel(
    const float* __restrict__ x, const float* __restrict__ guide,
    const float* __restrict__ qkv_w, const float* __restrict__ qkv_b,
    float* __restrict__ S)
{
    int blk = blockIdx.x;
    int b = blk >> 6, h = blk & 63;     // one output row per block
    __shared__ float tok[5][16][128];
    int t = threadIdx.x;
    int c = t & 127, par = t >> 7;
    const float4* wq = (const float4*)(qkv_w + (size_t)c*CC);
    const float4* wk = (const float4*)(qkv_w + (size_t)(CC + c)*CC);
    float bq = qkv_b[c], bk = qkv_b[CC + c];
    float sm0=0.f, sm1=0.f, sm2=0.f, sm3=0.f, sm4=0.f;
    const float* xb = x + (size_t)b*CC*HH*WW;
    const float* gb = guide + (size_t)b*CC*LL;
    for (int chv = 0; chv < 4; ++chv) {
        int w0 = chv << 4;
        stage_tokens(tok, xb, gb, h, w0, c, par);
        __syncthreads();
        float q0[8], k0[8], k1[8], k2[8], k3[8], k4[8];
        #pragma unroll
        for (int li = 0; li < 8; ++li) { q0[li]=bq; k0[li]=bk; k1[li]=bk; k2[li]=bk; k3[li]=bk; k4[li]=bk; }
        for (int i = 0; i < 32; ++i) {
            float4 wq4 = wq[i];
            float4 wk4 = wk[i];
            #pragma unroll
            for (int li = 0; li < 8; ++li) {
                int l = li*2 + par;
                float4 a0 = *(const float4*)&tok[0][l][i*4];
                float4 a1 = *(const float4*)&tok[1][l][i*4];
                float4 a2 = *(const float4*)&tok[2][l][i*4];
                float4 a3 = *(const float4*)&tok[3][l][i*4];
                float4 a4 = *(const float4*)&tok[4][l][i*4];
                q0[li] += dot4(wq4, a0);
                k0[li] += dot4(wk4, a0);
                k1[li] += dot4(wk4, a1);
                k2[li] += dot4(wk4, a2);
                k3[li] += dot4(wk4, a3);
                k4[li] += dot4(wk4, a4);
            }
        }
        #pragma unroll
        for (int li = 0; li < 8; ++li) {
            sm0 += q0[li]*k0[li];
            sm1 += q0[li]*k1[li];
            sm2 += q0[li]*k2[li];
            sm3 += q0[li]*k3[li];
            sm4 += q0[li]*k4[li];
        }
        __syncthreads();
    }
    float* Sp = S + (size_t)(b*CC + c)*5;
    atomicAdd(&Sp[0], sm0);
    atomicAdd(&Sp[1], sm1);
    atomicAdd(&Sp[2], sm2);
    atomicAdd(&Sp[3], sm3);
    atomicAdd(&Sp[4], sm4);
}

// ---- softmax over the 5 scores ----
__global__ __launch_bounds__(256) void softmax_kernel(
    const float* __restrict__ S, float* __restrict__ attn)
{
    int i = blockIdx.x*256 + threadIdx.x;
    if (i >= BB*CC) return;
    const float scale = 0.08838834764831845f;  // 1/sqrt(128)
    float s0 = S[i*5+0]*scale, s1 = S[i*5+1]*scale, s2 = S[i*5+2]*scale,
          s3 = S[i*5+3]*scale, s4 = S[i*5+4]*scale;
    float mx = fmaxf(fmaxf(fmaxf(s0,s1), fmaxf(s2,s3)), s4);
    float e0 = expf(s0-mx), e1 = expf(s1-mx), e2 = expf(s2-mx),
          e3 = expf(s3-mx), e4 = expf(s4-mx);
    float inv = 1.f/(e0+e1+e2+e3+e4);
    attn[i*5+0] = e0*inv; attn[i*5+1] = e1*inv; attn[i*5+2] = e2*inv;
    attn[i*5+3] = e3*inv; attn[i*5+4] = e4*inv;
}

// ---- phase B: v, out0 = sum_m attn*v_m, y = proj @ out0 + proj_b ----
__global__ __launch_bounds__(256) void out_kernel(
    const float* __restrict__ x, const float* __restrict__ guide,
    const float* __restrict__ qkv_w, const float* __restrict__ qkv_b,
    const float* __restrict__ attn, const float* __restrict__ proj_w,
    const float* __restrict__ proj_b, float* __restrict__ out)
{
    int blk = blockIdx.x;
    int b = blk >> 6, h = blk & 63;
    __shared__ float tok[5][16][128];
    __shared__ float olds[16][132];
    __shared__ float ylds[16][132];
    int t = threadIdx.x;
    int c = t & 127, par = t >> 7;
    const float4* wv = (const float4*)(qkv_w + (size_t)(2*CC + c)*CC);
    float bv = qkv_b[2*CC + c];
    float am0, am1, am2, am3, am4;
    {
        const float* ap = attn + (size_t)(b*CC + c)*5;
        am0 = ap[0]; am1 = ap[1]; am2 = ap[2]; am3 = ap[3]; am4 = ap[4];
    }
    const float4* pw = (const float4*)(proj_w + (size_t)c*CC);  // d = c row
    float pb = proj_b[c];
    const float* xb = x + (size_t)b*CC*HH*WW;
    const float* gb = guide + (size_t)b*CC*LL;
    for (int chv = 0; chv < 4; ++chv) {
        int w0 = chv << 4;
        stage_tokens(tok, xb, gb, h, w0, c, par);
        __syncthreads();
        // v phase: 5 dots per (c,l)
        float v0[8], v1[8], v2[8], v3[8], v4[8];
        #pragma unroll
        for (int li = 0; li < 8; ++li) { v0[li]=bv; v1[li]=bv; v2[li]=bv; v3[li]=bv; v4[li]=bv; }
        for (int i = 0; i < 32; ++i) {
            float4 wv4 = wv[i];
            #pragma unroll
            for (int li = 0; li < 8; ++li) {
                int l = li*2 + par;
                float4 a0 = *(const float4*)&tok[0][l][i*4];
                float4 a1 = *(const float4*)&tok[1][l][i*4];
                float4 a2 = *(const float4*)&tok[2][l][i*4];
                float4 a3 = *(const float4*)&tok[3][l][i*4];
                float4 a4 = *(const float4*)&tok[4][l][i*4];
                v0[li] += dot4(wv4, a0);
                v1[li] += dot4(wv4, a1);
                v2[li] += dot4(wv4, a2);
                v3[li] += dot4(wv4, a3);
                v4[li] += dot4(wv4, a4);
            }
        }
        #pragma unroll
        for (int li = 0; li < 8; ++li) {
            int l = li*2 + par;
            olds[l][c] = am0*v0[li] + am1*v1[li] + am2*v2[li] + am3*v3[li] + am4*v4[li];
        }
        __syncthreads();
        // projection: thread computes y for d=c across its 8 l
        float y[8];
        #pragma unroll
        for (int li = 0; li < 8; ++li) y[li] = pb;
        for (int i = 0; i < 32; ++i) {
            float4 pw4 = pw[i];
            #pragma unroll
            for (int li = 0; li < 8; ++li) {
                int l = li*2 + par;
                float4 o4 = *(const float4*)&olds[l][i*4];
                y[li] += dot4(pw4, o4);
            }
        }
        #pragma unroll
        for (int li = 0; li < 8; ++li) { int l = li*2 + par; ylds[l][c] = y[li]; }
        __syncthreads();
        // coalesced writeout: 2048 floats (128 d x 16 w)
        float* ob = out + (size_t)b*CC*LL + h*W2 + w0;
        #pragma unroll
        for (int i = 0; i < 8; ++i) {
            int idx = i*256 + t;
            int d = idx >> 4, pos = idx & 15;
            ob[(size_t)d*LL + pos] = ylds[pos][d];
        }
        __syncthreads();
    }
}

extern "C" void kernel_launch(void* const* d_in, const int* in_sizes, int n_in,
                              void* d_out, int out_size, void* d_ws, size_t ws_size,
                              hipStream_t stream) {
    const float* x        = (const float*)d_in[0];
    const float* bn_gamma = (const float*)d_in[1];
    const float* bn_beta  = (const float*)d_in[2];
    const float* bn_mean  = (const float*)d_in[3];
    const float* bn_var   = (const float*)d_in[4];
    const float* dw_w     = (const float*)d_in[5];
    const float* dw_b     = (const float*)d_in[6];
    const float* qkv_w    = (const float*)d_in[7];
    const float* qkv_b    = (const float*)d_in[8];
    const float* proj_w   = (const float*)d_in[9];
    const float* proj_b   = (const float*)d_in[10];
    float* out = (float*)d_out;

    float* guide = (float*)d_ws;
    float* S     = guide + (size_t)BB*CC*LL;
    float* attn  = S + BB*CC*5;

    zero_S<<<(BB*CC*5 + 255)/256, 256, 0, stream>>>(S);
    guide_kernel<<<dim3(BB*CC, 16), 256, 0, stream>>>(
        x, bn_gamma, bn_beta, bn_mean, bn_var, dw_w, dw_b, guide);
    s_kernel<<<BB*64, 256, 0, stream>>>(x, guide, qkv_w, qkv_b, S);
    softmax_kernel<<<(BB*CC + 255)/256, 256, 0, stream>>>(S, attn);
    out_kernel<<<BB*64, 256, 0, stream>>>(
        x, guide, qkv_w, qkv_b, attn, proj_w, proj_b, out);
}

// Round 3
// 437.590 us; speedup vs baseline: 1.8565x; 1.8565x over previous
//
#include <hip/hip_runtime.h>
#include <math.h>

#define BB 16
#define CC 128
#define HH 128
#define WW 128
#define H2 64
#define W2 64
#define LL 4096   // 64*64

typedef short short8 __attribute__((ext_vector_type(8)));
typedef float f32x4 __attribute__((ext_vector_type(4)));

__device__ __forceinline__ ushort f2bf(float f) {
    union { float f; unsigned u; } un; un.f = f;
    unsigned u = un.u;
    u += 0x7fffu + ((u >> 16) & 1u);   // RNE
    return (ushort)(u >> 16);
}
__device__ __forceinline__ float bf2f(ushort h) {
    union { unsigned u; float f; } un; un.u = ((unsigned)h) << 16;
    return un.f;
}

// ---- small prep: convert Wq/Wk to bf16, zero accumulators, cvec = proj@bv + pb ----
__global__ __launch_bounds__(256) void prep_small(
    const float* __restrict__ qkv_w, const float* __restrict__ qkv_b,
    const float* __restrict__ proj_w, const float* __restrict__ proj_b,
    ushort* __restrict__ wqk, float* __restrict__ zeroed, float* __restrict__ cvec)
{
    int t = threadIdx.x;
    int gid = blockIdx.x*256 + t;          // 128 blocks x 256 = 32768 = 2*128*128
    wqk[gid] = f2bf(qkv_w[gid]);
    if (blockIdx.x == 0) {
        for (int i = t; i < 2*BB*CC*5; i += 256) zeroed[i] = 0.f;  // Shat + Tsum
    }
    if (blockIdx.x == 1 && t < CC) {
        float s = proj_b[t];
        const float* pr = proj_w + t*CC;
        const float* bv = qkv_b + 2*CC;
        for (int c = 0; c < CC; ++c) s += pr[c]*bv[c];
        cvec[t] = s;
    }
}

// ---- guide = dwconv7x7_s2(gelu(bn(x))), stored bf16 [b][c][l] ----
__global__ __launch_bounds__(256) void guide_kernel(
    const float* __restrict__ x, const float* __restrict__ gamma,
    const float* __restrict__ beta, const float* __restrict__ mean,
    const float* __restrict__ var, const float* __restrict__ dww,
    const float* __restrict__ dwb, ushort* __restrict__ gw)
{
    int bc = blockIdx.x;
    int b = bc >> 7, c = bc & 127;
    int tile = blockIdx.y;
    int th0 = (tile >> 2) << 4, tw0 = (tile & 3) << 4;   // 16x16 output tile
    __shared__ float g[38][40];
    __shared__ float wsh[49];
    int t = threadIdx.x;
    if (t < 49) wsh[t] = dww[c*49 + t];
    float scl = gamma[c] * rsqrtf(var[c] + 1e-5f);
    float sft = beta[c] - mean[c]*scl;
    const float* xb = x + (size_t)(b*CC + c)*HH*WW;
    int ih0 = 2*th0 - 3, iw0 = 2*tw0 - 3;
    for (int idx = t; idx < 38*38; idx += 256) {
        int r = idx / 38, q = idx - r*38;
        int ih = ih0 + r, iw = iw0 + q;
        float v = 0.f;
        if ((unsigned)ih < (unsigned)HH && (unsigned)iw < (unsigned)WW) {
            float xv = xb[ih*WW + iw];
            xv = xv*scl + sft;
            v = 0.5f*xv*(1.f + erff(xv*0.70710678118654752f));
        }
        g[r][q] = v;
    }
    __syncthreads();
    int ol = t >> 4, ow = t & 15;
    float acc = dwb[c];
    #pragma unroll
    for (int kh = 0; kh < 7; ++kh)
        #pragma unroll
        for (int kw = 0; kw < 7; ++kw)
            acc += wsh[kh*7+kw] * g[2*ol+kh][2*ow+kw];
    gw[(size_t)(b*CC + c)*LL + (th0+ol)*W2 + (tw0+ow)] = f2bf(acc);
}

// ---- stage 5 tokens (bf16) for a 32-l chunk into LDS [m][l][c] with +8 pad ----
__device__ __forceinline__ void stage_tok(
    ushort* tok, const float* __restrict__ x, const ushort* __restrict__ gw,
    int b, int h, int w0, int t)
{
    // guide token (m=0): gw is [b][c][l], bf16 copy
    {
        int c = t & 127, half = t >> 7;
        const ushort* src = gw + ((size_t)(b*CC + c) << 12) + h*W2 + w0 + half*16;
        uint4 u0 = *(const uint4*)src;
        uint4 u1 = *(const uint4*)(src + 8);
        unsigned wd[8] = {u0.x, u0.y, u0.z, u0.w, u1.x, u1.y, u1.z, u1.w};
        int lb = half*16;
        #pragma unroll
        for (int k = 0; k < 8; ++k) {
            tok[(lb + 2*k    )*136 + c] = (ushort)wd[k];
            tok[(lb + 2*k + 1)*136 + c] = (ushort)(wd[k] >> 16);
        }
    }
    // x tokens (m=1..4): unfold parity s = s1*2 + s2
    {
        int c = t & 127, r = t >> 7;    // r = s1
        const float* xrow = x + ((size_t)(b*CC + c)*HH + (2*h + r))*WW + 2*w0;
        int mbase = 1 + r*2;
        #pragma unroll
        for (int q4 = 0; q4 < 16; ++q4) {
            float4 v = ((const float4*)xrow)[q4];
            int lq = q4*2;
            tok[((mbase    )*32 + lq    )*136 + c] = f2bf(v.x);
            tok[((mbase + 1)*32 + lq    )*136 + c] = f2bf(v.y);
            tok[((mbase    )*32 + lq + 1)*136 + c] = f2bf(v.z);
            tok[((mbase + 1)*32 + lq + 1)*136 + c] = f2bf(v.w);
        }
    }
}

// ---- phase A: Shat[b,c,m] += sum_l qhat0(c,l)*khat_m(c,l)  (MFMA) ----
__global__ __launch_bounds__(256) void s_mfma(
    const float* __restrict__ x, const ushort* __restrict__ gw,
    const ushort* __restrict__ wqk, float* __restrict__ Shat,
    float* __restrict__ Tsum)
{
    __shared__ __align__(16) ushort tok[5*32*136];
    int t = threadIdx.x;
    int b = blockIdx.x >> 7, chunk = blockIdx.x & 127;
    int h = chunk >> 1, w0 = (chunk & 1)*32;
    stage_tok(tok, x, gw, b, h, w0, t);
    __syncthreads();
    // token sums (for exact bias correction terms)
    for (int p = t; p < 5*CC; p += 256) {
        int m = p >> 7, c = p & 127;
        float s = 0.f;
        for (int l = 0; l < 32; ++l) s += bf2f(tok[(m*32 + l)*136 + c]);
        atomicAdd(&Tsum[(b*5 + m)*CC + c], s);
    }
    int lane = t & 63, wave = t >> 6;
    int strip = wave*32;
    const ushort* tb = tok + (lane & 15)*136 + (lane >> 4)*8;
    short8 aq[2][4], ak[2][4];
    #pragma unroll
    for (int mt = 0; mt < 2; ++mt)
        #pragma unroll
        for (int kt = 0; kt < 4; ++kt) {
            int off = (strip + mt*16 + (lane & 15))*CC + kt*32 + (lane >> 4)*8;
            aq[mt][kt] = *(const short8*)(wqk + off);
            ak[mt][kt] = *(const short8*)(wqk + CC*CC + off);
        }
    f32x4 q0[2][2] = {};
    #pragma unroll
    for (int kt = 0; kt < 4; ++kt)
        #pragma unroll
        for (int nt = 0; nt < 2; ++nt) {
            short8 bf = *(const short8*)(tb + (nt*16)*136 + kt*32);
            #pragma unroll
            for (int mt = 0; mt < 2; ++mt)
                q0[mt][nt] = __builtin_amdgcn_mfma_f32_16x16x32_bf16(aq[mt][kt], bf, q0[mt][nt], 0, 0, 0);
        }
    for (int m = 0; m < 5; ++m) {
        f32x4 ka[2][2] = {};
        #pragma unroll
        for (int kt = 0; kt < 4; ++kt)
            #pragma unroll
            for (int nt = 0; nt < 2; ++nt) {
                short8 bf = *(const short8*)(tb + (m*32 + nt*16)*136 + kt*32);
                #pragma unroll
                for (int mt = 0; mt < 2; ++mt)
                    ka[mt][nt] = __builtin_amdgcn_mfma_f32_16x16x32_bf16(ak[mt][kt], bf, ka[mt][nt], 0, 0, 0);
            }
        float sh[8];
        #pragma unroll
        for (int i = 0; i < 8; ++i) sh[i] = 0.f;
        #pragma unroll
        for (int mt = 0; mt < 2; ++mt)
            #pragma unroll
            for (int nt = 0; nt < 2; ++nt)
                #pragma unroll
                for (int r = 0; r < 4; ++r)
                    sh[mt*4 + r] += q0[mt][nt][r]*ka[mt][nt][r];
        #pragma unroll
        for (int i = 0; i < 8; ++i) {
            float v = sh[i];
            v += __shfl_xor(v, 1); v += __shfl_xor(v, 2);
            v += __shfl_xor(v, 4); v += __shfl_xor(v, 8);
            sh[i] = v;
        }
        if ((lane & 15) == 0) {
            int g = lane >> 4;
            #pragma unroll
            for (int mt = 0; mt < 2; ++mt)
                #pragma unroll
                for (int r = 0; r < 4; ++r) {
                    int c = strip + mt*16 + g*4 + r;
                    atomicAdd(&Shat[(b*CC + c)*5 + m], sh[mt*4 + r]);
                }
        }
    }
}

// ---- softmax with exact bias reconstruction ----
__global__ __launch_bounds__(256) void softmax2(
    const float* __restrict__ Shat, const float* __restrict__ Tsum,
    const float* __restrict__ qkv_w, const float* __restrict__ qkv_b,
    float* __restrict__ attn)
{
    int id = blockIdx.x*256 + threadIdx.x;
    if (id >= BB*CC) return;
    int b = id >> 7, c = id & 127;
    float bq = qkv_b[c], bk = qkv_b[CC + c];
    const float* wqr = qkv_w + c*CC;
    const float* wkr = qkv_w + (CC + c)*CC;
    const float* T = Tsum + b*5*CC;
    float t0dot = 0.f;
    for (int j = 0; j < CC; ++j) t0dot += wqr[j]*T[j];
    float s[5];
    for (int m = 0; m < 5; ++m) {
        float km = 0.f;
        const float* Tm = T + m*CC;
        for (int j = 0; j < CC; ++j) km += wkr[j]*Tm[j];
        s[m] = Shat[(b*CC + c)*5 + m] + bq*km + bk*t0dot + (float)LL*bq*bk;
    }
    const float scale = 0.08838834764831845f;  // 1/sqrt(128)
    float mx = s[0]*scale;
    #pragma unroll
    for (int m = 1; m < 5; ++m) mx = fmaxf(mx, s[m]*scale);
    float e[5], tot = 0.f;
    #pragma unroll
    for (int m = 0; m < 5; ++m) { e[m] = expf(s[m]*scale - mx); tot += e[m]; }
    float inv = 1.f/tot;
    #pragma unroll
    for (int m = 0; m < 5; ++m) attn[(b*CC + c)*5 + m] = e[m]*inv;
}

// ---- PW_m[b] = (proj .* attn_m) @ Wv, bf16 out ----
__global__ __launch_bounds__(256) void pw_kernel(
    const float* __restrict__ qkv_w, const float* __restrict__ proj_w,
    const float* __restrict__ attn, ushort* __restrict__ PW)
{
    __shared__ float attns[CC];
    __shared__ float wvs[32*CC];
    int blk = blockIdx.x;
    int b = blk / 5, m = blk % 5;
    int t = threadIdx.x;
    if (t < CC) attns[t] = attn[(b*CC + t)*5 + m];
    int d = t >> 1, cb = (t & 1)*64;
    float acc[64];
    #pragma unroll
    for (int j = 0; j < 64; ++j) acc[j] = 0.f;
    for (int cc0 = 0; cc0 < CC; cc0 += 32) {
        __syncthreads();
        for (int idx = t; idx < 32*CC; idx += 256) {
            int row = idx >> 7, col = idx & 127;
            wvs[idx] = qkv_w[(2*CC + cc0 + row)*CC + col];
        }
        __syncthreads();
        for (int cl = 0; cl < 32; ++cl) {
            int c = cc0 + cl;
            float a = proj_w[d*CC + c]*attns[c];
            const float* wr = wvs + cl*CC + cb;
            #pragma unroll
            for (int j = 0; j < 64; ++j) acc[j] += a*wr[j];
        }
    }
    ushort* dst = PW + ((size_t)(b*5 + m) << 14) + d*CC + cb;
    #pragma unroll
    for (int j = 0; j < 64; ++j) dst[j] = f2bf(acc[j]);
}

// ---- phase B: y = sum_m PW_m @ t_m + cvec  (MFMA) ----
__global__ __launch_bounds__(256) void y_mfma(
    const float* __restrict__ x, const ushort* __restrict__ gw,
    const ushort* __restrict__ PW, const float* __restrict__ cvec,
    float* __restrict__ out)
{
    __shared__ __align__(16) ushort tok[5*32*136];
    int t = threadIdx.x;
    int b = blockIdx.x >> 7, chunk = blockIdx.x & 127;
    int h = chunk >> 1, w0 = (chunk & 1)*32;
    stage_tok(tok, x, gw, b, h, w0, t);
    __syncthreads();
    int lane = t & 63, wave = t >> 6;
    int strip = wave*32;
    const ushort* tb = tok + (lane & 15)*136 + (lane >> 4)*8;
    f32x4 y[2][2] = {};
    for (int m = 0; m < 5; ++m) {
        const ushort* pwb = PW + ((size_t)(b*5 + m) << 14);
        short8 ap[2][4];
        #pragma unroll
        for (int mt = 0; mt < 2; ++mt)
            #pragma unroll
            for (int kt = 0; kt < 4; ++kt)
                ap[mt][kt] = *(const short8*)(pwb + (strip + mt*16 + (lane & 15))*CC + kt*32 + (lane >> 4)*8);
        #pragma unroll
        for (int kt = 0; kt < 4; ++kt)
            #pragma unroll
            for (int nt = 0; nt < 2; ++nt) {
                short8 bf = *(const short8*)(tb + (m*32 + nt*16)*136 + kt*32);
                #pragma unroll
                for (int mt = 0; mt < 2; ++mt)
                    y[mt][nt] = __builtin_amdgcn_mfma_f32_16x16x32_bf16(ap[mt][kt], bf, y[mt][nt], 0, 0, 0);
            }
    }
    __syncthreads();   // token LDS dead, reuse as fp32 transpose buffer
    float* ylds = (float*)tok;
    #pragma unroll
    for (int mt = 0; mt < 2; ++mt)
        #pragma unroll
        for (int nt = 0; nt < 2; ++nt)
            #pragma unroll
            for (int r = 0; r < 4; ++r) {
                int dl = strip + mt*16 + (lane >> 4)*4 + r;
                int ll = nt*16 + (lane & 15);
                ylds[dl*33 + ll] = y[mt][nt][r] + cvec[dl];
            }
    __syncthreads();
    int d = t >> 1, seg = t & 1;
    float* ob = out + ((size_t)(b*CC + d) << 12) + h*W2 + w0 + seg*16;
    const float* yr = ylds + d*33 + seg*16;
    #pragma unroll
    for (int j = 0; j < 16; ++j) ob[j] = yr[j];
}

extern "C" void kernel_launch(void* const* d_in, const int* in_sizes, int n_in,
                              void* d_out, int out_size, void* d_ws, size_t ws_size,
                              hipStream_t stream) {
    const float* x        = (const float*)d_in[0];
    const float* bn_gamma = (const float*)d_in[1];
    const float* bn_beta  = (const float*)d_in[2];
    const float* bn_mean  = (const float*)d_in[3];
    const float* bn_var   = (const float*)d_in[4];
    const float* dw_w     = (const float*)d_in[5];
    const float* dw_b     = (const float*)d_in[6];
    const float* qkv_w    = (const float*)d_in[7];
    const float* qkv_b    = (const float*)d_in[8];
    const float* proj_w   = (const float*)d_in[9];
    const float* proj_b   = (const float*)d_in[10];
    float* out = (float*)d_out;

    char* w = (char*)d_ws;
    ushort* gw  = (ushort*)w; w += (size_t)BB*CC*LL*2;      // 16 MB
    ushort* wqk = (ushort*)w; w += (size_t)2*CC*CC*2;       // 64 KB
    ushort* PW  = (ushort*)w; w += (size_t)BB*5*CC*CC*2;    // 2.5 MB
    float* Shat = (float*)w;  w += (size_t)BB*CC*5*4;
    float* Tsum = (float*)w;  w += (size_t)BB*5*CC*4;
    float* attn = (float*)w;  w += (size_t)BB*CC*5*4;
    float* cvec = (float*)w;  w += (size_t)CC*4;

    prep_small<<<128, 256, 0, stream>>>(qkv_w, qkv_b, proj_w, proj_b, wqk, Shat, cvec);
    guide_kernel<<<dim3(BB*CC, 16), 256, 0, stream>>>(
        x, bn_gamma, bn_beta, bn_mean, bn_var, dw_w, dw_b, gw);
    s_mfma<<<BB*128, 256, 0, stream>>>(x, gw, wqk, Shat, Tsum);
    softmax2<<<(BB*CC + 255)/256, 256, 0, stream>>>(Shat, Tsum, qkv_w, qkv_b, attn);
    pw_kernel<<<BB*5, 256, 0, stream>>>(qkv_w, proj_w, attn, PW);
    y_mfma<<<BB*128, 256, 0, stream>>>(x, gw, PW, cvec, out);
}

// Round 4
// 304.614 us; speedup vs baseline: 2.6670x; 1.4365x over previous
//
#include <hip/hip_runtime.h>
#include <math.h>

#define BB 16
#define CC 128
#define HH 128
#define WW 128
#define LL 4096

typedef short short8 __attribute__((ext_vector_type(8)));
typedef float f32x4 __attribute__((ext_vector_type(4)));

__device__ __forceinline__ ushort f2bf(float f) {
    union { float f; unsigned u; } un; un.f = f;
    unsigned u = un.u;
    u += 0x7fffu + ((u >> 16) & 1u);   // RNE
    return (ushort)(u >> 16);
}

// ---- prep: Wq/Wk -> bf16; cvec = proj@bv + proj_b ----
__global__ __launch_bounds__(256) void prep_small(
    const float* __restrict__ qkv_w, const float* __restrict__ qkv_b,
    const float* __restrict__ proj_w, const float* __restrict__ proj_b,
    ushort* __restrict__ wqk, float* __restrict__ cvec)
{
    int t = threadIdx.x;
    int gid = blockIdx.x*256 + t;          // 128 blocks * 256 = 32768 = 2*128*128
    wqk[gid] = f2bf(qkv_w[gid]);
    if (blockIdx.x == 1 && t < CC) {
        float s = proj_b[t];
        const float* pr = proj_w + t*CC;
        const float* bv = qkv_b + 2*CC;
        for (int c = 0; c < CC; ++c) s += pr[c]*bv[c];
        cvec[t] = s;
    }
}

// ---- guide = dwconv7x7_s2(gelu(bn(x))) (bf16 out) + fused token-sum partials ----
// Tpart[(bc*4 + ty)*5 + m]: m=0 guide-sum, m=1..4 raw-x parity sums (s1*2+s2)
__global__ __launch_bounds__(256) void guide_kernel(
    const float* __restrict__ x, const float* __restrict__ gamma,
    const float* __restrict__ beta, const float* __restrict__ mean,
    const float* __restrict__ var, const float* __restrict__ dww,
    const float* __restrict__ dwb, ushort* __restrict__ gw,
    float* __restrict__ Tpart)
{
    int bc = blockIdx.x;
    int b = bc >> 7, c = bc & 127;
    int ty = blockIdx.y, th0 = ty << 4;      // 16 output rows x 64 cols
    __shared__ float g[38][136];
    __shared__ float wsh[49];
    __shared__ float red[5][4];
    int t = threadIdx.x;
    int lane = t & 63, wave = t >> 6;
    if (t < 49) wsh[t] = dww[c*49 + t];
    float scl = gamma[c] * rsqrtf(var[c] + 1e-5f);
    float sft = beta[c] - mean[c]*scl;
    const float* xb = x + (size_t)(b*CC + c)*HH*WW;
    int ih0 = 2*th0 - 3;
    float a00=0.f, a01=0.f, a10=0.f, a11=0.f, gsum=0.f;
    for (int idx = t; idx < 38*134; idx += 256) {
        int rr = idx/134, q = idx - rr*134;
        int ih = ih0 + rr, iw = q - 3;
        float v = 0.f;
        if ((unsigned)ih < (unsigned)HH && (unsigned)iw < (unsigned)WW) {
            float xv = xb[ih*WW + iw];
            // core region of this tile: each x element counted exactly once over ty=0..3
            if (rr >= 3 && rr < 35 && q >= 3 && q < 131) {
                if (ih & 1) { if (iw & 1) a11 += xv; else a10 += xv; }
                else        { if (iw & 1) a01 += xv; else a00 += xv; }
            }
            xv = xv*scl + sft;
            v = 0.5f*xv*(1.f + erff(xv*0.70710678118654752f));
        }
        g[rr][q] = v;
    }
    __syncthreads();
    int ow = t & 63, olb = t >> 6;
    #pragma unroll
    for (int i = 0; i < 4; ++i) {
        int ol = olb*4 + i;
        float acc = dwb[c];
        #pragma unroll
        for (int kh = 0; kh < 7; ++kh)
            #pragma unroll
            for (int kw = 0; kw < 7; ++kw)
                acc += wsh[kh*7+kw] * g[2*ol+kh][2*ow+kw];
        gw[((size_t)(b*CC + c) << 12) + (th0+ol)*64 + ow] = f2bf(acc);
        gsum += acc;
    }
    float vals[5] = {gsum, a00, a01, a10, a11};
    #pragma unroll
    for (int v5 = 0; v5 < 5; ++v5) {
        float s = vals[v5];
        s += __shfl_xor(s, 1);  s += __shfl_xor(s, 2);
        s += __shfl_xor(s, 4);  s += __shfl_xor(s, 8);
        s += __shfl_xor(s, 16); s += __shfl_xor(s, 32);
        if (lane == 0) red[v5][wave] = s;
    }
    __syncthreads();
    if (t < 5)
        Tpart[((size_t)bc*4 + ty)*5 + t] = red[t][0]+red[t][1]+red[t][2]+red[t][3];
}

// ---- stage 5 tokens (bf16) for one 32-l chunk into LDS [m][l][c] pad+8, coalesced ----
__device__ __forceinline__ void stage_tok2(
    ushort* tok, const float* __restrict__ x, const ushort* __restrict__ gw,
    int b, int h, int whalf, int t)
{
    int c = t >> 1, r = t & 1;
    const float* xrow = x + ((size_t)(b*CC + c)*HH + (2*h + r))*WW + whalf*64;
    int m0 = (1 + 2*r)*32, m1 = (2 + 2*r)*32;
    #pragma unroll
    for (int i = 0; i < 16; ++i) {
        float4 v = ((const float4*)xrow)[i];
        tok[(m0 + 2*i    )*136 + c] = f2bf(v.x);
        tok[(m1 + 2*i    )*136 + c] = f2bf(v.y);
        tok[(m0 + 2*i + 1)*136 + c] = f2bf(v.z);
        tok[(m1 + 2*i + 1)*136 + c] = f2bf(v.w);
    }
    const ushort* gsrc = gw + ((size_t)(b*CC + c) << 12) + h*64 + whalf*32 + r*16;
    uint4 g0 = *(const uint4*)gsrc;
    uint4 g1 = *(const uint4*)(gsrc + 8);
    unsigned wd[8] = {g0.x,g0.y,g0.z,g0.w,g1.x,g1.y,g1.z,g1.w};
    #pragma unroll
    for (int k2 = 0; k2 < 8; ++k2) {
        tok[(r*16 + 2*k2    )*136 + c] = (ushort)wd[k2];
        tok[(r*16 + 2*k2 + 1)*136 + c] = (ushort)(wd[k2] >> 16);
    }
}

// ---- phase A: per-block partial S (no atomics) ----
__global__ __launch_bounds__(256) void s_kernel(
    const float* __restrict__ x, const ushort* __restrict__ gw,
    const ushort* __restrict__ wqk, float* __restrict__ Spart)
{
    __shared__ __align__(16) ushort tok[5*32*136];
    __shared__ float Sred[128*5];
    int t = threadIdx.x;
    int b = blockIdx.x >> 7, chunk = blockIdx.x & 127;
    int h = chunk >> 1, whalf = chunk & 1;
    stage_tok2(tok, x, gw, b, h, whalf, t);
    __syncthreads();
    int lane = t & 63, wave = t >> 6;
    int strip = wave*32;
    const ushort* tb = tok + (lane & 15)*136 + (lane >> 4)*8;
    short8 aq[2][4], ak[2][4];
    #pragma unroll
    for (int mt = 0; mt < 2; ++mt)
        #pragma unroll
        for (int kt = 0; kt < 4; ++kt) {
            int off = (strip + mt*16 + (lane & 15))*CC + kt*32 + (lane >> 4)*8;
            aq[mt][kt] = *(const short8*)(wqk + off);
            ak[mt][kt] = *(const short8*)(wqk + CC*CC + off);
        }
    f32x4 q0[2][2] = {};
    #pragma unroll
    for (int kt = 0; kt < 4; ++kt)
        #pragma unroll
        for (int nt = 0; nt < 2; ++nt) {
            short8 bf = *(const short8*)(tb + (nt*16)*136 + kt*32);
            #pragma unroll
            for (int mt = 0; mt < 2; ++mt)
                q0[mt][nt] = __builtin_amdgcn_mfma_f32_16x16x32_bf16(aq[mt][kt], bf, q0[mt][nt], 0, 0, 0);
        }
    for (int m = 0; m < 5; ++m) {
        f32x4 ka[2][2] = {};
        #pragma unroll
        for (int kt = 0; kt < 4; ++kt)
            #pragma unroll
            for (int nt = 0; nt < 2; ++nt) {
                short8 bf = *(const short8*)(tb + (m*32 + nt*16)*136 + kt*32);
                #pragma unroll
                for (int mt = 0; mt < 2; ++mt)
                    ka[mt][nt] = __builtin_amdgcn_mfma_f32_16x16x32_bf16(ak[mt][kt], bf, ka[mt][nt], 0, 0, 0);
            }
        float sh[8];
        #pragma unroll
        for (int i = 0; i < 8; ++i) sh[i] = 0.f;
        #pragma unroll
        for (int mt = 0; mt < 2; ++mt)
            #pragma unroll
            for (int nt = 0; nt < 2; ++nt)
                #pragma unroll
                for (int rr = 0; rr < 4; ++rr)
                    sh[mt*4 + rr] += q0[mt][nt][rr]*ka[mt][nt][rr];
        #pragma unroll
        for (int i = 0; i < 8; ++i) {
            float v = sh[i];
            v += __shfl_xor(v, 1); v += __shfl_xor(v, 2);
            v += __shfl_xor(v, 4); v += __shfl_xor(v, 8);
            sh[i] = v;
        }
        if ((lane & 15) == 0) {
            int g = lane >> 4;
            #pragma unroll
            for (int mt = 0; mt < 2; ++mt)
                #pragma unroll
                for (int rr = 0; rr < 4; ++rr)
                    Sred[(strip + mt*16 + g*4 + rr)*5 + m] = sh[mt*4 + rr];
        }
    }
    __syncthreads();
    float* Sp = Spart + (size_t)blockIdx.x*640;
    for (int i = t; i < 640; i += 256) Sp[i] = Sred[i];
}

// ---- reduce partials + exact bias + softmax ----
__global__ __launch_bounds__(256) void softmax_attn(
    const float* __restrict__ Spart, const float* __restrict__ Tpart,
    const float* __restrict__ qkv_w, const float* __restrict__ qkv_b,
    float* __restrict__ attn)
{
    __shared__ float TsumL[640];   // [m][c]
    __shared__ float SL[640];      // [c][m]
    int b = blockIdx.x, t = threadIdx.x;
    for (int i = t; i < 640; i += 256) {
        int m = i >> 7, j = i & 127;
        float s = 0.f;
        #pragma unroll
        for (int t4 = 0; t4 < 4; ++t4)
            s += Tpart[((size_t)(b*CC + j)*4 + t4)*5 + m];
        TsumL[i] = s;
        float s2 = 0.f;
        for (int ch = 0; ch < 128; ++ch)
            s2 += Spart[(size_t)(b*128 + ch)*640 + i];
        SL[i] = s2;
    }
    __syncthreads();
    if (t < CC) {
        int c = t;
        float bq = qkv_b[c], bk = qkv_b[CC + c];
        const float* wqr = qkv_w + c*CC;
        const float* wkr = qkv_w + (CC + c)*CC;
        float t0dot = 0.f;
        for (int j = 0; j < CC; ++j) t0dot += wqr[j]*TsumL[j];
        float s[5];
        #pragma unroll
        for (int m = 0; m < 5; ++m) {
            float km = 0.f;
            for (int j = 0; j < CC; ++j) km += wkr[j]*TsumL[m*128 + j];
            s[m] = SL[c*5 + m] + bq*km + bk*t0dot + (float)LL*bq*bk;
        }
        const float scale = 0.08838834764831845f;  // 1/sqrt(128)
        float mx = s[0]*scale;
        #pragma unroll
        for (int m = 1; m < 5; ++m) mx = fmaxf(mx, s[m]*scale);
        float e[5], tot = 0.f;
        #pragma unroll
        for (int m = 0; m < 5; ++m) { e[m] = expf(s[m]*scale - mx); tot += e[m]; }
        float inv = 1.f/tot;
        #pragma unroll
        for (int m = 0; m < 5; ++m) attn[(b*CC + c)*5 + m] = e[m]*inv;
    }
}

// ---- PW_m[b] = (proj .* attn_m) @ Wv, bf16 [b][m][c_out][c_in] ----
__global__ __launch_bounds__(256) void pw_kernel(
    const float* __restrict__ qkv_w, const float* __restrict__ proj_w,
    const float* __restrict__ attn, ushort* __restrict__ PW)
{
    __shared__ float attns[CC];
    __shared__ float wvs[32*CC];
    int blk = blockIdx.x;
    int b = blk / 5, m = blk % 5;
    int t = threadIdx.x;
    if (t < CC) attns[t] = attn[(b*CC + t)*5 + m];
    int d = t >> 1, cb = (t & 1)*64;
    float acc[64];
    #pragma unroll
    for (int j = 0; j < 64; ++j) acc[j] = 0.f;
    for (int cc0 = 0; cc0 < CC; cc0 += 32) {
        __syncthreads();
        for (int idx = t; idx < 32*CC; idx += 256) {
            int row = idx >> 7, col = idx & 127;
            wvs[idx] = qkv_w[(2*CC + cc0 + row)*CC + col];
        }
        __syncthreads();
        for (int cl = 0; cl < 32; ++cl) {
            int c = cc0 + cl;
            float a = proj_w[d*CC + c]*attns[c];
            const float* wr = wvs + cl*CC + cb;
            #pragma unroll
            for (int j = 0; j < 64; ++j) acc[j] += a*wr[j];
        }
    }
    ushort* dst = PW + ((size_t)(b*5 + m) << 14) + d*CC + cb;
    #pragma unroll
    for (int j = 0; j < 64; ++j) dst[j] = f2bf(acc[j]);
}

// ---- phase B: Y[l][c_out] = sum_{m,c} tok[m][l][c] * PW_m[c_out][c] + cvec ----
__global__ __launch_bounds__(256) void y_kernel(
    const float* __restrict__ x, const ushort* __restrict__ gw,
    const ushort* __restrict__ PW, const float* __restrict__ cvec,
    float* __restrict__ out)
{
    __shared__ __align__(16) ushort tok[5*32*136];   // reused as ylds[128][36] f32
    int t = threadIdx.x;
    int b = blockIdx.x >> 7, chunk = blockIdx.x & 127;
    int h = chunk >> 1, whalf = chunk & 1;
    stage_tok2(tok, x, gw, b, h, whalf, t);
    __syncthreads();
    int lane = t & 63, wave = t >> 6;
    const ushort* ta = tok + (lane & 15)*136 + (lane >> 4)*8;  // A: row=l, k=c
    f32x4 acc[2][2] = {};
    for (int m = 0; m < 5; ++m) {
        const ushort* pwb = PW + ((size_t)(b*5 + m) << 14)
                          + ((wave*32 + (lane & 15)) << 7) + ((lane >> 4) << 3);
        #pragma unroll
        for (int kt = 0; kt < 4; ++kt) {
            short8 a0 = *(const short8*)(ta + (m*32     )*136 + kt*32);
            short8 a1 = *(const short8*)(ta + (m*32 + 16)*136 + kt*32);
            short8 b0 = *(const short8*)(pwb + kt*32);
            short8 b1 = *(const short8*)(pwb + (16 << 7) + kt*32);
            acc[0][0] = __builtin_amdgcn_mfma_f32_16x16x32_bf16(a0, b0, acc[0][0], 0, 0, 0);
            acc[0][1] = __builtin_amdgcn_mfma_f32_16x16x32_bf16(a0, b1, acc[0][1], 0, 0, 0);
            acc[1][0] = __builtin_amdgcn_mfma_f32_16x16x32_bf16(a1, b0, acc[1][0], 0, 0, 0);
            acc[1][1] = __builtin_amdgcn_mfma_f32_16x16x32_bf16(a1, b1, acc[1][1], 0, 0, 0);
        }
    }
    __syncthreads();
    float* ylds = (float*)tok;   // [128][36]
    #pragma unroll
    for (int mt = 0; mt < 2; ++mt)
        #pragma unroll
        for (int ntl = 0; ntl < 2; ++ntl) {
            int cc = wave*32 + ntl*16 + (lane & 15);
            float cv = cvec[cc];
            #pragma unroll
            for (int rr = 0; rr < 4; ++rr) {
                int l = mt*16 + (lane >> 4)*4 + rr;
                ylds[cc*36 + l] = acc[mt][ntl][rr] + cv;
            }
        }
    __syncthreads();
    int c = t >> 1, half = t & 1;
    float* ob = out + ((size_t)(b*CC + c) << 12) + h*64 + whalf*32 + half*16;
    const float* yr = ylds + c*36 + half*16;
    #pragma unroll
    for (int j = 0; j < 4; ++j)
        ((float4*)ob)[j] = ((const float4*)yr)[j];
}

extern "C" void kernel_launch(void* const* d_in, const int* in_sizes, int n_in,
                              void* d_out, int out_size, void* d_ws, size_t ws_size,
                              hipStream_t stream) {
    const float* x        = (const float*)d_in[0];
    const float* bn_gamma = (const float*)d_in[1];
    const float* bn_beta  = (const float*)d_in[2];
    const float* bn_mean  = (const float*)d_in[3];
    const float* bn_var   = (const float*)d_in[4];
    const float* dw_w     = (const float*)d_in[5];
    const float* dw_b     = (const float*)d_in[6];
    const float* qkv_w    = (const float*)d_in[7];
    const float* qkv_b    = (const float*)d_in[8];
    const float* proj_w   = (const float*)d_in[9];
    const float* proj_b   = (const float*)d_in[10];
    float* out = (float*)d_out;

    char* w = (char*)d_ws;
    ushort* gw    = (ushort*)w; w += (size_t)BB*CC*LL*2;        // 16 MB
    ushort* wqk   = (ushort*)w; w += (size_t)2*CC*CC*2;         // 64 KB
    ushort* PW    = (ushort*)w; w += (size_t)BB*5*CC*CC*2;      // 2.5 MB
    float*  Spart = (float*)w;  w += (size_t)BB*128*640*4;      // 5.24 MB
    float*  Tpart = (float*)w;  w += (size_t)BB*CC*4*5*4;       // 160 KB
    float*  attn  = (float*)w;  w += (size_t)BB*CC*5*4;         // 40 KB
    float*  cvec  = (float*)w;  w += (size_t)CC*4;

    prep_small<<<128, 256, 0, stream>>>(qkv_w, qkv_b, proj_w, proj_b, wqk, cvec);
    guide_kernel<<<dim3(BB*CC, 4), 256, 0, stream>>>(
        x, bn_gamma, bn_beta, bn_mean, bn_var, dw_w, dw_b, gw, Tpart);
    s_kernel<<<BB*128, 256, 0, stream>>>(x, gw, wqk, Spart);
    softmax_attn<<<BB, 256, 0, stream>>>(Spart, Tpart, qkv_w, qkv_b, attn);
    pw_kernel<<<BB*5, 256, 0, stream>>>(qkv_w, proj_w, attn, PW);
    y_kernel<<<BB*128, 256, 0, stream>>>(x, gw, PW, cvec, out);
}

// Round 5
// 298.301 us; speedup vs baseline: 2.7234x; 1.0212x over previous
//
#include <hip/hip_runtime.h>
#include <math.h>

#define BB 16
#define CC 128
#define HH 128
#define WW 128
#define LL 4096

typedef short short8 __attribute__((ext_vector_type(8)));
typedef float f32x4 __attribute__((ext_vector_type(4)));

__device__ __forceinline__ ushort f2bf(float f) {
    union { float f; unsigned u; } un; un.f = f;
    unsigned u = un.u;
    u += 0x7fffu + ((u >> 16) & 1u);   // RNE
    return (ushort)(u >> 16);
}
__device__ __forceinline__ float bf2f(ushort h) {
    union { unsigned u; float f; } un; un.u = ((unsigned)h) << 16;
    return un.f;
}
// tanh-form GELU via sigmoid: x * sigmoid(2*0.79788456*(x+0.044715x^3))
// = x / (1 + exp2(-2*log2e*0.79788456*(x+0.044715x^3)))
__device__ __forceinline__ float fast_gelu(float xv) {
    float x2 = xv*xv;
    float arg = xv*(-2.3022100f - 0.1029436f*x2);
    float e = exp2f(arg);
    return xv*__builtin_amdgcn_rcpf(1.f + e);
}

// ---- prep: Wq/Wk -> bf16; cvec = proj@bv + proj_b ----
__global__ __launch_bounds__(256) void prep_small(
    const float* __restrict__ qkv_w, const float* __restrict__ qkv_b,
    const float* __restrict__ proj_w, const float* __restrict__ proj_b,
    ushort* __restrict__ wqk, float* __restrict__ cvec)
{
    int t = threadIdx.x;
    int gid = blockIdx.x*256 + t;          // 128 blocks * 256 = 32768 = 2*128*128
    wqk[gid] = f2bf(qkv_w[gid]);
    if (blockIdx.x == 1 && t < CC) {
        float s = proj_b[t];
        const float* pr = proj_w + t*CC;
        const float* bv = qkv_b + 2*CC;
        for (int c = 0; c < CC; ++c) s += pr[c]*bv[c];
        cvec[t] = s;
    }
}

// ---- guide = dwconv7x7_s2(gelu(bn(x))), bf16 out [b][c][64*64] ----
__global__ __launch_bounds__(256) void guide_kernel(
    const float* __restrict__ x, const float* __restrict__ gamma,
    const float* __restrict__ beta, const float* __restrict__ mean,
    const float* __restrict__ var, const float* __restrict__ dww,
    const float* __restrict__ dwb, ushort* __restrict__ gw)
{
    int bc = blockIdx.x;
    int b = bc >> 7, c = bc & 127;
    int ty = blockIdx.y, th0 = ty << 4;      // 16 output rows x 64 cols
    __shared__ float g[38][136];
    __shared__ float wsh[49];
    int t = threadIdx.x;
    if (t < 49) wsh[t] = dww[c*49 + t];
    float scl = gamma[c] * rsqrtf(var[c] + 1e-5f);
    float sft = beta[c] - mean[c]*scl;
    const float* xb = x + (size_t)(b*CC + c)*HH*WW;
    int ih0 = 2*th0 - 3;
    for (int idx = t; idx < 38*134; idx += 256) {
        int rr = idx/134, q = idx - rr*134;
        int ih = ih0 + rr, iw = q - 3;
        float v = 0.f;
        if ((unsigned)ih < (unsigned)HH && (unsigned)iw < (unsigned)WW) {
            float xv = xb[ih*WW + iw];
            v = fast_gelu(xv*scl + sft);
        }
        g[rr][q] = v;   // zero pad applied to conv INPUT (post-gelu), matches ref
    }
    __syncthreads();
    int ow = t & 63, olb = t >> 6;
    #pragma unroll
    for (int i = 0; i < 4; ++i) {
        int ol = olb*4 + i;
        float acc = dwb[c];
        #pragma unroll
        for (int kh = 0; kh < 7; ++kh)
            #pragma unroll
            for (int kw = 0; kw < 7; ++kw)
                acc += wsh[kh*7+kw] * g[2*ol+kh][2*ow+kw];
        gw[((size_t)(b*CC + c) << 12) + (th0+ol)*64 + ow] = f2bf(acc);
    }
}

// ---- stage 5 tokens (bf16) for one 32-l chunk into LDS [m][l][c] pad+8, coalesced ----
__device__ __forceinline__ void stage_tok2(
    ushort* tok, const float* __restrict__ x, const ushort* __restrict__ gw,
    int b, int h, int whalf, int t)
{
    int c = t >> 1, r = t & 1;
    const float* xrow = x + ((size_t)(b*CC + c)*HH + (2*h + r))*WW + whalf*64;
    int m0 = (1 + 2*r)*32, m1 = (2 + 2*r)*32;
    #pragma unroll
    for (int i = 0; i < 16; ++i) {
        float4 v = ((const float4*)xrow)[i];
        tok[(m0 + 2*i    )*136 + c] = f2bf(v.x);
        tok[(m1 + 2*i    )*136 + c] = f2bf(v.y);
        tok[(m0 + 2*i + 1)*136 + c] = f2bf(v.z);
        tok[(m1 + 2*i + 1)*136 + c] = f2bf(v.w);
    }
    const ushort* gsrc = gw + ((size_t)(b*CC + c) << 12) + h*64 + whalf*32 + r*16;
    uint4 g0 = *(const uint4*)gsrc;
    uint4 g1 = *(const uint4*)(gsrc + 8);
    unsigned wd[8] = {g0.x,g0.y,g0.z,g0.w,g1.x,g1.y,g1.z,g1.w};
    #pragma unroll
    for (int k2 = 0; k2 < 8; ++k2) {
        tok[(r*16 + 2*k2    )*136 + c] = (ushort)wd[k2];
        tok[(r*16 + 2*k2 + 1)*136 + c] = (ushort)(wd[k2] >> 16);
    }
}

// ---- phase A: per-block partial S (640) + token-sum partial T (640), 2 chunks/block ----
__global__ __launch_bounds__(256) void s_kernel(
    const float* __restrict__ x, const ushort* __restrict__ gw,
    const ushort* __restrict__ wqk, float* __restrict__ Spart)
{
    __shared__ __align__(16) ushort tok[5*32*136];
    __shared__ float Sred[640];
    int t = threadIdx.x;
    int blk = blockIdx.x;
    int b = blk >> 6, pair = blk & 63;
    int lane = t & 63, wave = t >> 6;
    int strip = wave*32;
    short8 aq[2][4], ak[2][4];
    #pragma unroll
    for (int mt = 0; mt < 2; ++mt)
        #pragma unroll
        for (int kt = 0; kt < 4; ++kt) {
            int off = (strip + mt*16 + (lane & 15))*CC + kt*32 + (lane >> 4)*8;
            aq[mt][kt] = *(const short8*)(wqk + off);
            ak[mt][kt] = *(const short8*)(wqk + CC*CC + off);
        }
    float sacc[5][8];
    #pragma unroll
    for (int m = 0; m < 5; ++m)
        #pragma unroll
        for (int i = 0; i < 8; ++i) sacc[m][i] = 0.f;
    float tacc[3] = {0.f, 0.f, 0.f};
    const ushort* tb = tok + (lane & 15)*136 + (lane >> 4)*8;

    #pragma unroll
    for (int cidx = 0; cidx < 2; ++cidx) {
        int chunk = pair*2 + cidx;
        int h = chunk >> 1, whalf = chunk & 1;
        if (cidx) __syncthreads();
        stage_tok2(tok, x, gw, b, h, whalf, t);
        __syncthreads();
        // token-sum partials from staged bf16 tokens
        #pragma unroll
        for (int j = 0; j < 3; ++j) {
            int i = t + j*256;
            if (i < 640) {
                int m = i >> 7, cch = i & 127;
                float s = 0.f;
                for (int l = 0; l < 32; ++l) s += bf2f(tok[(m*32 + l)*136 + cch]);
                tacc[j] += s;
            }
        }
        f32x4 q0[2][2] = {};
        #pragma unroll
        for (int kt = 0; kt < 4; ++kt)
            #pragma unroll
            for (int nt = 0; nt < 2; ++nt) {
                short8 bf = *(const short8*)(tb + (nt*16)*136 + kt*32);
                #pragma unroll
                for (int mt = 0; mt < 2; ++mt)
                    q0[mt][nt] = __builtin_amdgcn_mfma_f32_16x16x32_bf16(aq[mt][kt], bf, q0[mt][nt], 0, 0, 0);
            }
        #pragma unroll
        for (int m = 0; m < 5; ++m) {
            f32x4 ka[2][2] = {};
            #pragma unroll
            for (int kt = 0; kt < 4; ++kt)
                #pragma unroll
                for (int nt = 0; nt < 2; ++nt) {
                    short8 bf = *(const short8*)(tb + (m*32 + nt*16)*136 + kt*32);
                    #pragma unroll
                    for (int mt = 0; mt < 2; ++mt)
                        ka[mt][nt] = __builtin_amdgcn_mfma_f32_16x16x32_bf16(ak[mt][kt], bf, ka[mt][nt], 0, 0, 0);
                }
            #pragma unroll
            for (int mt = 0; mt < 2; ++mt)
                #pragma unroll
                for (int nt = 0; nt < 2; ++nt)
                    #pragma unroll
                    for (int rr = 0; rr < 4; ++rr)
                        sacc[m][mt*4 + rr] += q0[mt][nt][rr]*ka[mt][nt][rr];
        }
    }
    #pragma unroll
    for (int m = 0; m < 5; ++m)
        #pragma unroll
        for (int i = 0; i < 8; ++i) {
            float v = sacc[m][i];
            v += __shfl_xor(v, 1); v += __shfl_xor(v, 2);
            v += __shfl_xor(v, 4); v += __shfl_xor(v, 8);
            if ((lane & 15) == 0)
                Sred[(strip + (i >> 2)*16 + (lane >> 4)*4 + (i & 3))*5 + m] = v;
        }
    __syncthreads();
    float* Sp = Spart + (size_t)blk*1280;
    for (int i = t; i < 640; i += 256) Sp[i] = Sred[i];
    #pragma unroll
    for (int j = 0; j < 3; ++j) {
        int i = t + j*256;
        if (i < 640) Sp[640 + i] = tacc[j];
    }
}

// ---- reduce partials + exact bias + softmax ----
__global__ __launch_bounds__(256) void softmax_attn(
    const float* __restrict__ Spart,
    const float* __restrict__ qkv_w, const float* __restrict__ qkv_b,
    float* __restrict__ attn)
{
    __shared__ float TsumL[640];   // [m][c]
    __shared__ float SL[640];      // [c][m]
    int b = blockIdx.x, t = threadIdx.x;
    for (int i = t; i < 640; i += 256) {
        float s2 = 0.f, ts = 0.f;
        for (int p = 0; p < 64; ++p) {
            const float* row = Spart + (size_t)(b*64 + p)*1280;
            s2 += row[i];
            ts += row[640 + i];
        }
        SL[i] = s2;
        TsumL[i] = ts;
    }
    __syncthreads();
    if (t < CC) {
        int c = t;
        float bq = qkv_b[c], bk = qkv_b[CC + c];
        const float* wqr = qkv_w + c*CC;
        const float* wkr = qkv_w + (CC + c)*CC;
        float t0dot = 0.f;
        for (int j = 0; j < CC; ++j) t0dot += wqr[j]*TsumL[j];
        float s[5];
        #pragma unroll
        for (int m = 0; m < 5; ++m) {
            float km = 0.f;
            for (int j = 0; j < CC; ++j) km += wkr[j]*TsumL[m*128 + j];
            s[m] = SL[c*5 + m] + bq*km + bk*t0dot + (float)LL*bq*bk;
        }
        const float scale = 0.08838834764831845f;  // 1/sqrt(128)
        float mx = s[0]*scale;
        #pragma unroll
        for (int m = 1; m < 5; ++m) mx = fmaxf(mx, s[m]*scale);
        float e[5], tot = 0.f;
        #pragma unroll
        for (int m = 0; m < 5; ++m) { e[m] = expf(s[m]*scale - mx); tot += e[m]; }
        float inv = 1.f/tot;
        #pragma unroll
        for (int m = 0; m < 5; ++m) attn[(b*CC + c)*5 + m] = e[m]*inv;
    }
}

// ---- PW_m[b] = (proj .* attn_m) @ Wv, bf16 [b][m][c_out][c_in] ----
__global__ __launch_bounds__(256) void pw_kernel(
    const float* __restrict__ qkv_w, const float* __restrict__ proj_w,
    const float* __restrict__ attn, ushort* __restrict__ PW)
{
    __shared__ float attns[CC];
    __shared__ float wvs[32*CC];
    int blk = blockIdx.x;
    int b = blk / 5, m = blk % 5;
    int t = threadIdx.x;
    if (t < CC) attns[t] = attn[(b*CC + t)*5 + m];
    int d = t >> 1, cb = (t & 1)*64;
    float acc[64];
    #pragma unroll
    for (int j = 0; j < 64; ++j) acc[j] = 0.f;
    for (int cc0 = 0; cc0 < CC; cc0 += 32) {
        __syncthreads();
        for (int idx = t; idx < 32*CC; idx += 256) {
            int row = idx >> 7, col = idx & 127;
            wvs[idx] = qkv_w[(2*CC + cc0 + row)*CC + col];
        }
        __syncthreads();
        for (int cl = 0; cl < 32; ++cl) {
            int c = cc0 + cl;
            float a = proj_w[d*CC + c]*attns[c];
            const float* wr = wvs + cl*CC + cb;
            #pragma unroll
            for (int j = 0; j < 64; ++j) acc[j] += a*wr[j];
        }
    }
    ushort* dst = PW + ((size_t)(b*5 + m) << 14) + d*CC + cb;
    #pragma unroll
    for (int j = 0; j < 64; ++j) dst[j] = f2bf(acc[j]);
}

// ---- phase B: Y[l][c_out] = sum_{m,c} tok[m][l][c] * PW_m[c_out][c] + cvec ----
__global__ __launch_bounds__(256) void y_kernel(
    const float* __restrict__ x, const ushort* __restrict__ gw,
    const ushort* __restrict__ PW, const float* __restrict__ cvec,
    float* __restrict__ out)
{
    __shared__ __align__(16) ushort tok[5*32*136];   // reused as ylds[128][36] f32
    int t = threadIdx.x;
    int b = blockIdx.x >> 7, chunk = blockIdx.x & 127;
    int h = chunk >> 1, whalf = chunk & 1;
    stage_tok2(tok, x, gw, b, h, whalf, t);
    __syncthreads();
    int lane = t & 63, wave = t >> 6;
    const ushort* ta = tok + (lane & 15)*136 + (lane >> 4)*8;  // A: row=l, k=c
    f32x4 acc[2][2] = {};
    #pragma unroll
    for (int m = 0; m < 5; ++m) {
        const ushort* pwb = PW + ((size_t)(b*5 + m) << 14)
                          + ((wave*32 + (lane & 15)) << 7) + ((lane >> 4) << 3);
        #pragma unroll
        for (int kt = 0; kt < 4; ++kt) {
            short8 a0 = *(const short8*)(ta + (m*32     )*136 + kt*32);
            short8 a1 = *(const short8*)(ta + (m*32 + 16)*136 + kt*32);
            short8 b0 = *(const short8*)(pwb + kt*32);
            short8 b1 = *(const short8*)(pwb + (16 << 7) + kt*32);
            acc[0][0] = __builtin_amdgcn_mfma_f32_16x16x32_bf16(a0, b0, acc[0][0], 0, 0, 0);
            acc[0][1] = __builtin_amdgcn_mfma_f32_16x16x32_bf16(a0, b1, acc[0][1], 0, 0, 0);
            acc[1][0] = __builtin_amdgcn_mfma_f32_16x16x32_bf16(a1, b0, acc[1][0], 0, 0, 0);
            acc[1][1] = __builtin_amdgcn_mfma_f32_16x16x32_bf16(a1, b1, acc[1][1], 0, 0, 0);
        }
    }
    __syncthreads();
    float* ylds = (float*)tok;   // [128][36]
    #pragma unroll
    for (int mt = 0; mt < 2; ++mt)
        #pragma unroll
        for (int ntl = 0; ntl < 2; ++ntl) {
            int cc = wave*32 + ntl*16 + (lane & 15);
            float cv = cvec[cc];
            #pragma unroll
            for (int rr = 0; rr < 4; ++rr) {
                int l = mt*16 + (lane >> 4)*4 + rr;
                ylds[cc*36 + l] = acc[mt][ntl][rr] + cv;
            }
        }
    __syncthreads();
    int c = t >> 1, half = t & 1;
    float* ob = out + ((size_t)(b*CC + c) << 12) + h*64 + whalf*32 + half*16;
    const float* yr = ylds + c*36 + half*16;
    #pragma unroll
    for (int j = 0; j < 4; ++j)
        ((float4*)ob)[j] = ((const float4*)yr)[j];
}

extern "C" void kernel_launch(void* const* d_in, const int* in_sizes, int n_in,
                              void* d_out, int out_size, void* d_ws, size_t ws_size,
                              hipStream_t stream) {
    const float* x        = (const float*)d_in[0];
    const float* bn_gamma = (const float*)d_in[1];
    const float* bn_beta  = (const float*)d_in[2];
    const float* bn_mean  = (const float*)d_in[3];
    const float* bn_var   = (const float*)d_in[4];
    const float* dw_w     = (const float*)d_in[5];
    const float* dw_b     = (const float*)d_in[6];
    const float* qkv_w    = (const float*)d_in[7];
    const float* qkv_b    = (const float*)d_in[8];
    const float* proj_w   = (const float*)d_in[9];
    const float* proj_b   = (const float*)d_in[10];
    float* out = (float*)d_out;

    char* w = (char*)d_ws;
    ushort* gw    = (ushort*)w; w += (size_t)BB*CC*LL*2;        // 16 MB
    ushort* wqk   = (ushort*)w; w += (size_t)2*CC*CC*2;         // 64 KB
    ushort* PW    = (ushort*)w; w += (size_t)BB*5*CC*CC*2;      // 2.5 MB
    float*  Spart = (float*)w;  w += (size_t)1024*1280*4;       // 5.24 MB
    float*  attn  = (float*)w;  w += (size_t)BB*CC*5*4;         // 40 KB
    float*  cvec  = (float*)w;  w += (size_t)CC*4;

    prep_small<<<128, 256, 0, stream>>>(qkv_w, qkv_b, proj_w, proj_b, wqk, cvec);
    guide_kernel<<<dim3(BB*CC, 4), 256, 0, stream>>>(
        x, bn_gamma, bn_beta, bn_mean, bn_var, dw_w, dw_b, gw);
    s_kernel<<<1024, 256, 0, stream>>>(x, gw, wqk, Spart);
    softmax_attn<<<BB, 256, 0, stream>>>(Spart, qkv_w, qkv_b, attn);
    pw_kernel<<<BB*5, 256, 0, stream>>>(qkv_w, proj_w, attn, PW);
    y_kernel<<<BB*128, 256, 0, stream>>>(x, gw, PW, cvec, out);
}